// Round 17
// baseline (2316.231 us; speedup 1.0000x reference)
//
#include <hip/hip_runtime.h>

#define BB 64
#define TT 512
#define EE 512
#define RR 2048
#define CPW 32    // columns per scan workgroup
#define RPG 16    // rows (batch) per group
#define NWGS 256  // 4 groups x 64 col-WGs
#define FPAD 16   // flag padding: 16 u32 = 64 B/flag
#define SLOT2 (BB * RR * 2)      // one S-history slot (f16, 256KB)
#define GRP2  (RPG * RR * 2)     // group slice within a slot (64KB)
#define SPIN_CAP (1 << 20)       // watchdog: fail fast instead of hanging

typedef _Float16 f16;
typedef f16 f16x8 __attribute__((ext_vector_type(8)));
typedef float f32x4 __attribute__((ext_vector_type(4)));

__device__ __forceinline__ float fast_tanh(float v) {
  float e = __expf(2.0f * v);
  return 1.0f - 2.0f / (e + 1.0f);
}

// write-through device-coherent 2B store (R2-R16 proven): lands at L3
__device__ __forceinline__ void storeS(f16* p, f16 h) {
  union { f16 h; unsigned short s; } u;
  u.h = h;
  __hip_atomic_store((unsigned short*)p, u.s, __ATOMIC_RELAXED, __HIP_MEMORY_SCOPE_AGENT);
}

__device__ __forceinline__ unsigned flag_ld(const unsigned* p) {
  return __hip_atomic_load(p, __ATOMIC_RELAXED, __HIP_MEMORY_SCOPE_AGENT);
}
__device__ __forceinline__ void flag_st(unsigned* p, unsigned v) {
  __hip_atomic_store(p, v, __ATOMIC_RELAXED, __HIP_MEMORY_SCOPE_AGENT);
}

__device__ __forceinline__ unsigned lds_ld(const unsigned* p) {
  return __hip_atomic_load(p, __ATOMIC_RELAXED, __HIP_MEMORY_SCOPE_WORKGROUP);
}
__device__ __forceinline__ void lds_add(unsigned* p) {
  __hip_atomic_fetch_add(p, 1u, __ATOMIC_RELAXED, __HIP_MEMORY_SCOPE_WORKGROUP);
}

// 8 plain cached 16B loads, imm offsets 0..448 (single-assignment makes caching safe)
__device__ __forceinline__ void issue8(f16x8* dst, unsigned voff, const f16* sbase) {
#pragma unroll
  for (int i = 0; i < 8; ++i)
    asm volatile("global_load_dwordx4 %0, %1, %2 offset:%c3"
                 : "=v"(dst[i]) : "v"(voff), "s"(sbase), "i"(64 * i) : "memory");
}
// 2 plain cached 16B loads (this wave's emb u-chunks), imm 0 / 64
__device__ __forceinline__ void issue2(f16x8* dst, unsigned voff, const f16* sbase) {
  asm volatile("global_load_dwordx4 %0, %1, %2"
               : "=v"(dst[0]) : "v"(voff), "s"(sbase) : "memory");
  asm volatile("global_load_dwordx4 %0, %1, %2 offset:64"
               : "=v"(dst[1]) : "v"(voff), "s"(sbase) : "memory");
}

template <int N>
__device__ __forceinline__ void wait_vm() {
  asm volatile("s_waitcnt vmcnt(%c0)" :: "i"(N) : "memory");
  __builtin_amdgcn_sched_barrier(0);   // rule #18
}

// ---------------- prep kernels ----------------

__global__ void prep_emb(const int* __restrict__ x, const float* __restrict__ ew,
                         f16* __restrict__ emb) {
  const int row = blockIdx.x;            // token index (b*T + t)
  const int tok = x[row];
  const float4* src = (const float4*)(ew + (size_t)tok * EE);
  f16* dst = emb + (size_t)row * EE;
  const int i = threadIdx.x;             // 128 threads, 4 f16 each
  float4 v = src[i];
  union { f16 h[4]; unsigned long long u; } p;
  p.h[0] = (f16)v.x; p.h[1] = (f16)v.y; p.h[2] = (f16)v.z; p.h[3] = (f16)v.w;
  ((unsigned long long*)dst)[i] = p.u;
}

__global__ void prep_winT(const float* __restrict__ Win, f16* __restrict__ WinT) {
  const int i = blockIdx.x * blockDim.x + threadIdx.x;  // over EE*RR
  if (i < EE * RR) {
    const int k = i / RR, n = i % RR;
    WinT[(size_t)n * EE + k] = (f16)Win[i];
  }
}

// ---------------- fused scan: recurrence + distributed inline projection ----------
// R16 core (single-assignment S-history slots, group-local, zero per-step
// fences, distributed u-projection riding the 8-way reduce) with the SECOND
// per-step barrier replaced by a monotone LDS counter:
// * each wave, after its own store + vmcnt(0), bumps `done` once per step.
// * rotating publisher wave (wv == tau&7): lane 0 spins done >= 8*tau, then
//   publishes the group flag. Only that wave absorbs the intra-WG drain
//   skew; the other 7 waves proceed straight to the next octet poll.
// * red-buffer reuse guard: before writing partials for step tau, spin
//   done >= 8*(tau-1) — placed after the MFMA phase (~1.5us after the prior
//   reads), so it is virtually always pre-satisfied.
// Deadlock-free: all post-barrier work is WG-local and terminating; the only
// cross-WG wait is the octet poll (R6-proven). Numerics bit-identical to R16.

__launch_bounds__(512, 1)
__global__ void scan_kernel(const float* __restrict__ R, f16* __restrict__ Sh,
                            const f16* __restrict__ emb, const f16* __restrict__ WinT,
                            unsigned* __restrict__ flg) {
  __shared__ __align__(16) char ldsbuf[CPW * RR * 2 + 16 * 1040];  // 128K Rt + reduce buf
  __shared__ unsigned done;
  f16* Rt = (f16*)ldsbuf;
  const char* RtB = (const char*)ldsbuf;

  const int wg = blockIdx.x;
  const int xcd = wg & 7;                        // heuristic (perf only)
  const int grp = xcd >> 1;                      // group on XCD pair
  const int cw = ((wg >> 3) << 1) | (wg & 1);    // 0..63 within group
  const int nbase = cw * CPW;
  const int rbase = grp * RPG;
  const int tid = threadIdx.x;
  const int wv = tid >> 6, l = tid & 63;
  unsigned* gflags = flg + (size_t)grp * 64 * FPAD;
  unsigned* myflag = gflags + cw * FPAD;
  f16* Sg = Sh + (size_t)grp * (RPG * RR);       // group slice base (within slot 0)

  if (tid == 0) done = 0u;

  // prologue: one-time L1/L2 invalidate (cross-launch residue)
  __builtin_amdgcn_fence(__ATOMIC_ACQUIRE, "agent");

  const int r16 = l & 15, kb = l >> 4;
  const int mm = tid >> 5, cc = tid & 31;        // output element (row, col)
  // reduce-read coords for (mm, cc)
  const int ntr = cc >> 4;
  const int lred = (cc & 15) | ((mm >> 2) << 4);
  const int jred = mm & 3;
  char* red = ldsbuf + CPW * RR * 2;

  // R column slice -> LDS (chunked conflict-free layout), once
  {
    const int c = tid & 31, kst = tid >> 5;
    for (int k = kst; k < RR; k += 16) {
      const float v = R[(size_t)k * RR + nbase + c];
      const int idx = ((k >> 5) << 10) + ((c >> 4) << 9) +
                      (((c & 15) << 2) + ((k >> 3) & 3)) * 8 + (k & 7);
      Rt[idx] = (f16)v;
    }
  }

  // WinT fragments for this wave's 2 u-chunks x 2 col-halves (16 VGPRs)
  f16x8 wfr[2][2];
#pragma unroll
  for (int c2 = 0; c2 < 2; ++c2)
#pragma unroll
    for (int nt = 0; nt < 2; ++nt)
      wfr[c2][nt] = *(const f16x8*)&WinT[(size_t)(nbase + nt * 16 + r16) * EE +
                                         (2 * wv + c2) * 32 + kb * 8];

  // emb byte offset for this wave's chunks at t: voffE0 + t*EE*2
  const unsigned voffE0 =
      (unsigned)((((size_t)(rbase + r16) * TT) * EE + 2 * wv * 32 + kb * 8) * 2);

  // ---- tau = 1: S_1 = tanh(u_0) via the distributed-reduce machinery ----
  {
    f16x8 ebuf[2];
    issue2(ebuf, voffE0 /* t=0 */, emb);
    wait_vm<0>();
    f32x4 a0 = {0.f, 0.f, 0.f, 0.f}, a1 = {0.f, 0.f, 0.f, 0.f};
#pragma unroll
    for (int c2 = 0; c2 < 2; ++c2) {
      a0 = __builtin_amdgcn_mfma_f32_16x16x32_f16(ebuf[c2], wfr[c2][0], a0, 0, 0, 0);
      a1 = __builtin_amdgcn_mfma_f32_16x16x32_f16(ebuf[c2], wfr[c2][1], a1, 0, 0, 0);
    }
    *(f32x4*)(red + (wv * 2 + 0) * 1040 + l * 16) = a0;
    *(f32x4*)(red + (wv * 2 + 1) * 1040 + l * 16) = a1;
    __syncthreads();                       // also covers Rt writes + done init
    float s = 0.f;
#pragma unroll
    for (int w = 0; w < 8; ++w)
      s += *(const float*)(red + (w * 2 + ntr) * 1040 + lred * 16 + jred * 4);
    storeS(&Sg[(size_t)mm * RR + nbase + cc], (f16)fast_tanh(s));
    wait_vm<0>();                          // own stores at L3
    if (l == 0) lds_add(&done);
    if (wv == 1) {                         // publisher for step 1
      if (l == 0) {
        unsigned d; int gd = 0;
        do { d = lds_ld(&done); } while (d < 8u && ++gd < (1 << 22));
        flag_st(myflag, 1u);
      }
    }
  }

  const int kblk = (wv + cw) & 7;          // k-rotation: de-hotspot + octet polls
  const unsigned voffA = (unsigned)(((r16 * RR) + (kblk << 8) + kb * 8) * 2);
  const int bb0 = (r16 * 4 + kb) * 16;     // byte within 1024B chunk row

  f16x8 abuf[8];

  for (int tau = 2; tau <= TT; ++tau) {
    const unsigned need = (unsigned)(tau - 1);

    // per-wave poll of this wave's 8 producers (R6-proven shape)
    {
      const unsigned* pp = &gflags[(size_t)(kblk * 8 + (l & 7)) * FPAD];
      unsigned fv = flag_ld(pp);
      int gd = 0;
      while (!__all(fv >= need) && ++gd < SPIN_CAP) {
        __builtin_amdgcn_s_sleep(1);
        fv = flag_ld(pp);
      }
    }

    const f16* sprev = Sh + (size_t)(tau - 2) * (BB * RR) + (size_t)grp * (RPG * RR);
    f16* snext = (f16*)((char*)Sh + (size_t)(tau - 1) * SLOT2) + (size_t)grp * (RPG * RR);

    // queue: A0..A7 (state), E0,E1 (emb chunks for u_{tau-1})
    issue8(abuf, voffA, sprev);
    f16x8 ebuf[2];
    issue2(ebuf, voffE0 + (unsigned)((tau - 1) * (EE * 2)), emb);

    f32x4 acc0 = {0.f, 0.f, 0.f, 0.f}, acc1 = {0.f, 0.f, 0.f, 0.f};
#define KSTEP(ks)                                                              \
  {                                                                            \
    const int kc = (kblk << 3) + (ks);                                         \
    f16x8 b0 = *(const f16x8*)(RtB + kc * 2048 + bb0);                         \
    f16x8 b1 = *(const f16x8*)(RtB + kc * 2048 + 1024 + bb0);                  \
    acc0 = __builtin_amdgcn_mfma_f32_16x16x32_f16(abuf[ks], b0, acc0, 0, 0, 0);\
    acc1 = __builtin_amdgcn_mfma_f32_16x16x32_f16(abuf[ks], b1, acc1, 0, 0, 0);\
  }
    wait_vm<6>();                            // A0..A3 ready (A4..7,E out)
    KSTEP(0) KSTEP(1) KSTEP(2) KSTEP(3)
    wait_vm<2>();                            // A4..A7 ready (E out)
    KSTEP(4) KSTEP(5) KSTEP(6) KSTEP(7)
#undef KSTEP
    wait_vm<0>();                            // E0,E1 ready
#pragma unroll
    for (int c2 = 0; c2 < 2; ++c2) {         // fold u-partials into acc
      acc0 = __builtin_amdgcn_mfma_f32_16x16x32_f16(ebuf[c2], wfr[c2][0], acc0, 0, 0, 0);
      acc1 = __builtin_amdgcn_mfma_f32_16x16x32_f16(ebuf[c2], wfr[c2][1], acc1, 0, 0, 0);
    }

    // red-buffer free guard: prior step's reads done (normally pre-satisfied)
    {
      unsigned d; int gd = 0;
      do { d = lds_ld(&done); } while (d < 8u * (unsigned)(tau - 1) && ++gd < (1 << 22));
    }

    // partial accumulators -> LDS (padded per-wave copies), 8-way reduce
    *(f32x4*)(red + (wv * 2 + 0) * 1040 + l * 16) = acc0;
    *(f32x4*)(red + (wv * 2 + 1) * 1040 + l * 16) = acc1;
    __syncthreads();                         // barrier-1 (only barrier/step)
    {
      float s = 0.f;
#pragma unroll
      for (int w = 0; w < 8; ++w)
        s += *(const float*)(red + (w * 2 + ntr) * 1040 + lred * 16 + jred * 4);
      storeS(&snext[(size_t)mm * RR + nbase + cc], (f16)fast_tanh(s));
    }
    wait_vm<0>();                            // own stores at L3 (E long retired)
    if (l == 0) lds_add(&done);              // this wave done with step tau
    if (wv == (tau & 7)) {                   // rotating publisher wave
      if (l == 0) {
        unsigned d; int gd = 0;
        do { d = lds_ld(&done); } while (d < 8u * (unsigned)tau && ++gd < (1 << 22));
        flag_st(myflag, (unsigned)tau);
      }
    }
    // other 7 waves proceed straight to the next octet poll
  }
}

// ---------------- LayerNorm (group-local final-state layout) ----------------

__launch_bounds__(256, 1)
__global__ void ln_kernel(const char* __restrict__ slotbase, const float* __restrict__ gamma,
                          const float* __restrict__ beta, float* __restrict__ out) {
  const int b = blockIdx.x;
  const int tid = threadIdx.x;
  const f16* row = (const f16*)(slotbase + (size_t)(b >> 4) * GRP2) + (size_t)(b & 15) * RR;
  float vals[8];
  float lsum = 0.f, lsq = 0.f;
#pragma unroll
  for (int i = 0; i < 8; ++i) {
    float v = (float)row[tid + i * 256];
    vals[i] = v; lsum += v; lsq += v * v;
  }
#pragma unroll
  for (int off = 32; off >= 1; off >>= 1) {
    lsum += __shfl_xor(lsum, off);
    lsq  += __shfl_xor(lsq, off);
  }
  __shared__ float ps[4], pq[4];
  __shared__ float mu_s, rstd_s;
  const int wv = tid >> 6, l = tid & 63;
  if (l == 0) { ps[wv] = lsum; pq[wv] = lsq; }
  __syncthreads();
  if (tid == 0) {
    float s = 0.f, q = 0.f;
    for (int i = 0; i < 4; ++i) { s += ps[i]; q += pq[i]; }
    const float mu = s / RR;
    const float var = q / RR - mu * mu;
    mu_s = mu; rstd_s = rsqrtf(var + 1e-5f);
  }
  __syncthreads();
  const float mu = mu_s, rstd = rstd_s;
#pragma unroll
  for (int i = 0; i < 8; ++i) {
    const int idx = tid + i * 256;
    out[(size_t)b * RR + idx] = (vals[i] - mu) * rstd * gamma[idx] + beta[idx];
  }
}

// ---------------- launch ----------------

extern "C" void kernel_launch(void* const* d_in, const int* in_sizes, int n_in,
                              void* d_out, int out_size, void* d_ws, size_t ws_size,
                              hipStream_t stream) {
  const int*   x     = (const int*)d_in[0];
  const float* ew    = (const float*)d_in[1];
  const float* Rm    = (const float*)d_in[2];
  const float* Win   = (const float*)d_in[3];
  const float* gamma = (const float*)d_in[4];
  const float* beta  = (const float*)d_in[5];

  const size_t SH_OFF  = 0;                           // f16  512 slots x 256KB = 128MB
  const size_t EMB_OFF = (size_t)TT * SLOT2;          // f16  32768*512*2 = 32MB
  const size_t WT_OFF  = EMB_OFF + 33554432;          // f16  2048*512*2  = 2MB
  const size_t FLG_OFF = WT_OFF + 2097152;            // u32  256 flags x 64B
  const size_t NEED    = FLG_OFF + 16384;
  if (ws_size < NEED) {
    hipMemsetAsync(d_out, 0, (size_t)out_size * 4, stream);
    return;
  }
  char* ws = (char*)d_ws;
  f16*      Shist = (f16*)(ws + SH_OFF);
  f16*      emb   = (f16*)(ws + EMB_OFF);
  f16*      WinT  = (f16*)(ws + WT_OFF);
  unsigned* flg   = (unsigned*)(ws + FLG_OFF);

  hipMemsetAsync(flg, 0, 16384, stream);   // flags reset each launch (replay-safe)
  prep_emb<<<BB * TT, 128, 0, stream>>>(x, ew, emb);
  prep_winT<<<(EE * RR) / 256, 256, 0, stream>>>(Win, WinT);
  scan_kernel<<<NWGS, 512, 0, stream>>>(Rm, Shist, emb, WinT, flg);
  // S_512 lives in slot 511 (group-local slices)
  ln_kernel<<<BB, 256, 0, stream>>>(ws + (size_t)(TT - 1) * SLOT2,
                                    gamma, beta, (float*)d_out);
}

// Round 18
// 2057.261 us; speedup vs baseline: 1.1259x; 1.1259x over previous
//
#include <hip/hip_runtime.h>

#define BB 64
#define TT 512
#define EE 512
#define RR 2048
#define CPW 32    // columns per scan workgroup
#define RPG 16    // rows (batch) per group
#define NWGS 256  // 4 groups x 64 col-WGs
#define FPAD 16   // flag padding: 16 u32 = 64 B/flag
#define SLOT2 (BB * RR * 2)      // one S-history slot (f16, 256KB)
#define GRP2  (RPG * RR * 2)     // group slice within a slot (64KB)
#define SPIN_CAP (1 << 20)       // watchdog: fail fast instead of hanging

typedef _Float16 f16;
typedef f16 f16x8 __attribute__((ext_vector_type(8)));
typedef float f32x4 __attribute__((ext_vector_type(4)));

__device__ __forceinline__ float fast_tanh(float v) {
  float e = __expf(2.0f * v);
  return 1.0f - 2.0f / (e + 1.0f);
}

// write-through device-coherent 2B store (R2-R16 proven): lands at L3
__device__ __forceinline__ void storeS(f16* p, f16 h) {
  union { f16 h; unsigned short s; } u;
  u.h = h;
  __hip_atomic_store((unsigned short*)p, u.s, __ATOMIC_RELAXED, __HIP_MEMORY_SCOPE_AGENT);
}

__device__ __forceinline__ unsigned flag_ld(const unsigned* p) {
  return __hip_atomic_load(p, __ATOMIC_RELAXED, __HIP_MEMORY_SCOPE_AGENT);
}
__device__ __forceinline__ void flag_st(unsigned* p, unsigned v) {
  __hip_atomic_store(p, v, __ATOMIC_RELAXED, __HIP_MEMORY_SCOPE_AGENT);
}

// 8 plain cached 16B loads, imm offsets 0..448 (single-assignment makes caching safe)
__device__ __forceinline__ void issue8(f16x8* dst, unsigned voff, const f16* sbase) {
#pragma unroll
  for (int i = 0; i < 8; ++i)
    asm volatile("global_load_dwordx4 %0, %1, %2 offset:%c3"
                 : "=v"(dst[i]) : "v"(voff), "s"(sbase), "i"(64 * i) : "memory");
}
// 2 plain cached 16B loads (this wave's emb u-chunks), imm 0 / 64
__device__ __forceinline__ void issue2(f16x8* dst, unsigned voff, const f16* sbase) {
  asm volatile("global_load_dwordx4 %0, %1, %2"
               : "=v"(dst[0]) : "v"(voff), "s"(sbase) : "memory");
  asm volatile("global_load_dwordx4 %0, %1, %2 offset:64"
               : "=v"(dst[1]) : "v"(voff), "s"(sbase) : "memory");
}

template <int N>
__device__ __forceinline__ void wait_vm() {
  asm volatile("s_waitcnt vmcnt(%c0)" :: "i"(N) : "memory");
  __builtin_amdgcn_sched_barrier(0);   // rule #18
}

// ---------------- prep kernels ----------------

__global__ void prep_emb(const int* __restrict__ x, const float* __restrict__ ew,
                         f16* __restrict__ emb) {
  const int row = blockIdx.x;            // token index (b*T + t)
  const int tok = x[row];
  const float4* src = (const float4*)(ew + (size_t)tok * EE);
  f16* dst = emb + (size_t)row * EE;
  const int i = threadIdx.x;             // 128 threads, 4 f16 each
  float4 v = src[i];
  union { f16 h[4]; unsigned long long u; } p;
  p.h[0] = (f16)v.x; p.h[1] = (f16)v.y; p.h[2] = (f16)v.z; p.h[3] = (f16)v.w;
  ((unsigned long long*)dst)[i] = p.u;
}

__global__ void prep_winT(const float* __restrict__ Win, f16* __restrict__ WinT) {
  const int i = blockIdx.x * blockDim.x + threadIdx.x;  // over EE*RR
  if (i < EE * RR) {
    const int k = i / RR, n = i % RR;
    WinT[(size_t)n * EE + k] = (f16)Win[i];
  }
}

// ---------------- fused scan: recurrence + distributed inline projection ----------
// R16 (best proven: 1.867 ms total): single-assignment S-history slots,
// group-local, zero per-step fences, R6 flag protocol, u-projection
// DISTRIBUTED across all 8 waves:
// * u's K=512 split into 16 chunks of 32; wave wv owns chunks {2wv, 2wv+1}.
//   Per step it appends 2 emb loads to the A-load queue and folds 4 MFMAs
//   (chunk x col-half, WinT frags pinned in 16 VGPRs) into acc0/acc1. The
//   u-sum rides the EXISTING 8-way LDS reduce — no separate u-phase, no
//   wave asymmetry, ~0.05us/step added serial cost.
// * Step tau=1 uses the same machinery: acc = u_0 partials only -> reduce ->
//   S_1 = tanh(sum).
// * S_tau lives in a fresh 256KB slot per step (group-local slice): cached
//   A-loads are the launch's first cached touch => always fresh from L3.
//   No U buffer, no proj_gemm kernel, no per-step fences.
// R17 lesson: do NOT touch the two-barrier step shape — every sync
// restructure tested (R7/R10/R11/R17) was neutral or worse.

__launch_bounds__(512, 1)
__global__ void scan_kernel(const float* __restrict__ R, f16* __restrict__ Sh,
                            const f16* __restrict__ emb, const f16* __restrict__ WinT,
                            unsigned* __restrict__ flg) {
  __shared__ __align__(16) char ldsbuf[CPW * RR * 2 + 16 * 1040];  // 128K Rt + reduce buf
  f16* Rt = (f16*)ldsbuf;
  const char* RtB = (const char*)ldsbuf;

  const int wg = blockIdx.x;
  const int xcd = wg & 7;                        // heuristic (perf only)
  const int grp = xcd >> 1;                      // group on XCD pair
  const int cw = ((wg >> 3) << 1) | (wg & 1);    // 0..63 within group
  const int nbase = cw * CPW;
  const int rbase = grp * RPG;
  const int tid = threadIdx.x;
  const int wv = tid >> 6, l = tid & 63;
  unsigned* gflags = flg + (size_t)grp * 64 * FPAD;
  unsigned* myflag = gflags + cw * FPAD;
  f16* Sg = Sh + (size_t)grp * (RPG * RR);       // group slice base (within slot 0)

  // prologue: one-time L1/L2 invalidate (cross-launch residue)
  __builtin_amdgcn_fence(__ATOMIC_ACQUIRE, "agent");

  const int r16 = l & 15, kb = l >> 4;
  const int mm = tid >> 5, cc = tid & 31;        // output element (row, col)
  // reduce-read coords for (mm, cc)
  const int ntr = cc >> 4;
  const int lred = (cc & 15) | ((mm >> 2) << 4);
  const int jred = mm & 3;
  char* red = ldsbuf + CPW * RR * 2;

  // R column slice -> LDS (chunked conflict-free layout), once
  {
    const int c = tid & 31, kst = tid >> 5;
    for (int k = kst; k < RR; k += 16) {
      const float v = R[(size_t)k * RR + nbase + c];
      const int idx = ((k >> 5) << 10) + ((c >> 4) << 9) +
                      (((c & 15) << 2) + ((k >> 3) & 3)) * 8 + (k & 7);
      Rt[idx] = (f16)v;
    }
  }

  // WinT fragments for this wave's 2 u-chunks x 2 col-halves (16 VGPRs)
  f16x8 wfr[2][2];
#pragma unroll
  for (int c2 = 0; c2 < 2; ++c2)
#pragma unroll
    for (int nt = 0; nt < 2; ++nt)
      wfr[c2][nt] = *(const f16x8*)&WinT[(size_t)(nbase + nt * 16 + r16) * EE +
                                         (2 * wv + c2) * 32 + kb * 8];

  // emb byte offset for this wave's chunks at t: voffE0 + t*EE*2
  const unsigned voffE0 =
      (unsigned)((((size_t)(rbase + r16) * TT) * EE + 2 * wv * 32 + kb * 8) * 2);

  // ---- tau = 1: S_1 = tanh(u_0) via the same distributed-reduce machinery ----
  {
    f16x8 ebuf[2];
    issue2(ebuf, voffE0 /* t=0 */, emb);
    wait_vm<0>();
    f32x4 a0 = {0.f, 0.f, 0.f, 0.f}, a1 = {0.f, 0.f, 0.f, 0.f};
#pragma unroll
    for (int c2 = 0; c2 < 2; ++c2) {
      a0 = __builtin_amdgcn_mfma_f32_16x16x32_f16(ebuf[c2], wfr[c2][0], a0, 0, 0, 0);
      a1 = __builtin_amdgcn_mfma_f32_16x16x32_f16(ebuf[c2], wfr[c2][1], a1, 0, 0, 0);
    }
    *(f32x4*)(red + (wv * 2 + 0) * 1040 + l * 16) = a0;
    *(f32x4*)(red + (wv * 2 + 1) * 1040 + l * 16) = a1;
    __syncthreads();                       // also covers the Rt writes above
    float s = 0.f;
#pragma unroll
    for (int w = 0; w < 8; ++w)
      s += *(const float*)(red + (w * 2 + ntr) * 1040 + lred * 16 + jred * 4);
    storeS(&Sg[(size_t)mm * RR + nbase + cc], (f16)fast_tanh(s));
    __syncthreads();                       // drains stores + red reads done
    if (tid == 0) flag_st(myflag, 1u);
  }

  const int kblk = (wv + cw) & 7;          // k-rotation: de-hotspot + octet polls
  const unsigned voffA = (unsigned)(((r16 * RR) + (kblk << 8) + kb * 8) * 2);
  const int bb0 = (r16 * 4 + kb) * 16;     // byte within 1024B chunk row

  f16x8 abuf[8];

  for (int tau = 2; tau <= TT; ++tau) {
    const unsigned need = (unsigned)(tau - 1);

    // per-wave poll of this wave's 8 producers (R6-proven shape); clean queue
    {
      const unsigned* pp = &gflags[(size_t)(kblk * 8 + (l & 7)) * FPAD];
      unsigned fv = flag_ld(pp);
      int gd = 0;
      while (!__all(fv >= need) && ++gd < SPIN_CAP) {
        __builtin_amdgcn_s_sleep(1);
        fv = flag_ld(pp);
      }
    }

    const f16* sprev = Sh + (size_t)(tau - 2) * (BB * RR) + (size_t)grp * (RPG * RR);
    f16* snext = (f16*)((char*)Sh + (size_t)(tau - 1) * SLOT2) + (size_t)grp * (RPG * RR);

    // queue: A0..A7 (state), E0,E1 (emb chunks for u_{tau-1})
    issue8(abuf, voffA, sprev);
    f16x8 ebuf[2];
    issue2(ebuf, voffE0 + (unsigned)((tau - 1) * (EE * 2)), emb);

    f32x4 acc0 = {0.f, 0.f, 0.f, 0.f}, acc1 = {0.f, 0.f, 0.f, 0.f};
#define KSTEP(ks)                                                              \
  {                                                                            \
    const int kc = (kblk << 3) + (ks);                                         \
    f16x8 b0 = *(const f16x8*)(RtB + kc * 2048 + bb0);                         \
    f16x8 b1 = *(const f16x8*)(RtB + kc * 2048 + 1024 + bb0);                  \
    acc0 = __builtin_amdgcn_mfma_f32_16x16x32_f16(abuf[ks], b0, acc0, 0, 0, 0);\
    acc1 = __builtin_amdgcn_mfma_f32_16x16x32_f16(abuf[ks], b1, acc1, 0, 0, 0);\
  }
    wait_vm<6>();                            // A0..A3 ready (A4..7,E out)
    KSTEP(0) KSTEP(1) KSTEP(2) KSTEP(3)
    wait_vm<2>();                            // A4..A7 ready (E out)
    KSTEP(4) KSTEP(5) KSTEP(6) KSTEP(7)
#undef KSTEP
    wait_vm<0>();                            // E0,E1 ready
#pragma unroll
    for (int c2 = 0; c2 < 2; ++c2) {         // fold u-partials into acc
      acc0 = __builtin_amdgcn_mfma_f32_16x16x32_f16(ebuf[c2], wfr[c2][0], acc0, 0, 0, 0);
      acc1 = __builtin_amdgcn_mfma_f32_16x16x32_f16(ebuf[c2], wfr[c2][1], acc1, 0, 0, 0);
    }

    // partial accumulators -> LDS (padded per-wave copies), 8-way reduce
    *(f32x4*)(red + (wv * 2 + 0) * 1040 + l * 16) = acc0;
    *(f32x4*)(red + (wv * 2 + 1) * 1040 + l * 16) = acc1;
    __syncthreads();
    {
      float s = 0.f;
#pragma unroll
      for (int w = 0; w < 8; ++w)
        s += *(const float*)(red + (w * 2 + ntr) * 1040 + lred * 16 + jred * 4);
      storeS(&snext[(size_t)mm * RR + nbase + cc], (f16)fast_tanh(s));
    }
    __syncthreads();                         // drains stores (vmcnt0 at barrier)
    if (tid == 0) flag_st(myflag, (unsigned)tau);
  }
}

// ---------------- LayerNorm (group-local final-state layout) ----------------

__launch_bounds__(256, 1)
__global__ void ln_kernel(const char* __restrict__ slotbase, const float* __restrict__ gamma,
                          const float* __restrict__ beta, float* __restrict__ out) {
  const int b = blockIdx.x;
  const int tid = threadIdx.x;
  const f16* row = (const f16*)(slotbase + (size_t)(b >> 4) * GRP2) + (size_t)(b & 15) * RR;
  float vals[8];
  float lsum = 0.f, lsq = 0.f;
#pragma unroll
  for (int i = 0; i < 8; ++i) {
    float v = (float)row[tid + i * 256];
    vals[i] = v; lsum += v; lsq += v * v;
  }
#pragma unroll
  for (int off = 32; off >= 1; off >>= 1) {
    lsum += __shfl_xor(lsum, off);
    lsq  += __shfl_xor(lsq, off);
  }
  __shared__ float ps[4], pq[4];
  __shared__ float mu_s, rstd_s;
  const int wv = tid >> 6, l = tid & 63;
  if (l == 0) { ps[wv] = lsum; pq[wv] = lsq; }
  __syncthreads();
  if (tid == 0) {
    float s = 0.f, q = 0.f;
    for (int i = 0; i < 4; ++i) { s += ps[i]; q += pq[i]; }
    const float mu = s / RR;
    const float var = q / RR - mu * mu;
    mu_s = mu; rstd_s = rsqrtf(var + 1e-5f);
  }
  __syncthreads();
  const float mu = mu_s, rstd = rstd_s;
#pragma unroll
  for (int i = 0; i < 8; ++i) {
    const int idx = tid + i * 256;
    out[(size_t)b * RR + idx] = (vals[i] - mu) * rstd * gamma[idx] + beta[idx];
  }
}

// ---------------- launch ----------------

extern "C" void kernel_launch(void* const* d_in, const int* in_sizes, int n_in,
                              void* d_out, int out_size, void* d_ws, size_t ws_size,
                              hipStream_t stream) {
  const int*   x     = (const int*)d_in[0];
  const float* ew    = (const float*)d_in[1];
  const float* Rm    = (const float*)d_in[2];
  const float* Win   = (const float*)d_in[3];
  const float* gamma = (const float*)d_in[4];
  const float* beta  = (const float*)d_in[5];

  const size_t SH_OFF  = 0;                           // f16  512 slots x 256KB = 128MB
  const size_t EMB_OFF = (size_t)TT * SLOT2;          // f16  32768*512*2 = 32MB
  const size_t WT_OFF  = EMB_OFF + 33554432;          // f16  2048*512*2  = 2MB
  const size_t FLG_OFF = WT_OFF + 2097152;            // u32  256 flags x 64B
  const size_t NEED    = FLG_OFF + 16384;
  if (ws_size < NEED) {
    hipMemsetAsync(d_out, 0, (size_t)out_size * 4, stream);
    return;
  }
  char* ws = (char*)d_ws;
  f16*      Shist = (f16*)(ws + SH_OFF);
  f16*      emb   = (f16*)(ws + EMB_OFF);
  f16*      WinT  = (f16*)(ws + WT_OFF);
  unsigned* flg   = (unsigned*)(ws + FLG_OFF);

  hipMemsetAsync(flg, 0, 16384, stream);   // flags reset each launch (replay-safe)
  prep_emb<<<BB * TT, 128, 0, stream>>>(x, ew, emb);
  prep_winT<<<(EE * RR) / 256, 256, 0, stream>>>(Win, WinT);
  scan_kernel<<<NWGS, 512, 0, stream>>>(Rm, Shist, emb, WinT, flg);
  // S_512 lives in slot 511 (group-local slices)
  ln_kernel<<<BB, 256, 0, stream>>>(ws + (size_t)(TT - 1) * SLOT2,
                                    gamma, beta, (float*)d_out);
}